// Round 9
// baseline (323.719 us; speedup 1.0000x reference)
//
#include <hip/hip_runtime.h>
#include <hip/hip_bf16.h>
#include <stdint.h>
#include <type_traits>

#define NHEAD  16
#define DMODEL 1024
#define BATCH  2
#define SEQ    2048
#define DH     64
#define MROWS  (BATCH*SEQ)   // 4096

typedef __attribute__((ext_vector_type(8))) short bf16x8;
typedef __attribute__((ext_vector_type(4))) float f32x4;

__device__ inline short f2bs(float f) {
    __hip_bfloat16 h = __float2bfloat16(f);
    return *reinterpret_cast<short*>(&h);
}

// async global -> LDS, 16B per lane. LDS dest = wave-uniform base + lane*16.
__device__ inline void async16(const void* g, void* l) {
    __builtin_amdgcn_global_load_lds(
        (__attribute__((address_space(1))) void*)g,
        (__attribute__((address_space(3))) void*)l, 16, 0, 0);
}

// ------------- fp32 -> bf16 pre-convert: weights (4M) + q,k,v inputs (12M) -------------
__global__ __launch_bounds__(256)
void convert_all(const float* __restrict__ Wq, const float* __restrict__ Wk,
                 const float* __restrict__ Wv, const float* __restrict__ Wo,
                 const float* __restrict__ q, const float* __restrict__ k,
                 const float* __restrict__ v,
                 __hip_bfloat16* __restrict__ Wqkv, __hip_bfloat16* __restrict__ Wob,
                 __hip_bfloat16* __restrict__ qb, __hip_bfloat16* __restrict__ kb,
                 __hip_bfloat16* __restrict__ vb)
{
    const int idx = (blockIdx.x * 256 + threadIdx.x) * 8;
    const float* src;
    __hip_bfloat16* dst;
    if (idx < 3 * 1048576) {
        const int g = idx >> 20;
        src = (g == 0 ? Wq : (g == 1 ? Wk : Wv)) + (idx & 1048575);
        dst = Wqkv + idx;
    } else if (idx < 4 * 1048576) {
        src = Wo + (idx - 3 * 1048576);
        dst = Wob + (idx - 3 * 1048576);
    } else if (idx < 8 * 1048576) {
        src = q + (idx - 4 * 1048576);
        dst = qb + (idx - 4 * 1048576);
    } else if (idx < 12 * 1048576) {
        src = k + (idx - 8 * 1048576);
        dst = kb + (idx - 8 * 1048576);
    } else {
        src = v + (idx - 12 * 1048576);
        dst = vb + (idx - 12 * 1048576);
    }
    float4 f0 = *(const float4*)src;
    float4 f1 = *(const float4*)(src + 4);
    short o[8];
    o[0] = f2bs(f0.x); o[1] = f2bs(f0.y); o[2] = f2bs(f0.z); o[3] = f2bs(f0.w);
    o[4] = f2bs(f1.x); o[5] = f2bs(f1.y); o[6] = f2bs(f1.z); o[7] = f2bs(f1.w);
    *(uint4*)dst = *(uint4*)o;
}

// ---------------- V-projection transpose: vp[4096][1024] -> vt[b][h][64][2048] ----------------
__global__ __launch_bounds__(256)
void transpose_v(const __hip_bfloat16* __restrict__ vp, __hip_bfloat16* __restrict__ vt)
{
    __shared__ short L[64 * 72];
    const int t  = threadIdx.x;
    const int st = blockIdx.x & 63;
    const int ht = blockIdx.x >> 6;
    {
        const int r = t >> 2, cs = (t & 3) * 16;
        const __hip_bfloat16* src = vp + (size_t)(st * 64 + r) * DMODEL + ht * 64 + cs;
        *(uint4*)&L[r * 72 + cs]     = *(const uint4*)src;
        *(uint4*)&L[r * 72 + cs + 8] = *(const uint4*)(src + 8);
    }
    __syncthreads();
    const int d  = t >> 2;
    const int ss = (t & 3) * 16;
    const int m0 = st * 64;
    const int b  = m0 >> 11;
    const int s0 = (m0 & 2047) + ss;
    short o[16];
#pragma unroll
    for (int i = 0; i < 16; i++) o[i] = L[(ss + i) * 72 + d];
    __hip_bfloat16* dst = vt + ((size_t)((b * NHEAD + ht) * DH + d)) * SEQ + s0;
    *(uint4*)dst       = *(uint4*)&o[0];
    *(uint4*)(dst + 8) = *(uint4*)&o[8];
}

// ---------------- GEMM: C[:,grp] = A_grp[M,K] @ B[N,K]^T + bias (all-bf16 inputs) ----------------
template <typename TC>
__global__ __launch_bounds__(256, 3)
void gemm_bt(const __hip_bfloat16* __restrict__ A0, const __hip_bfloat16* __restrict__ A1,
             const __hip_bfloat16* __restrict__ A2,
             const __hip_bfloat16* __restrict__ B,
             const float* __restrict__ b0, const float* __restrict__ b1, const float* __restrict__ b2,
             TC* __restrict__ C0, TC* __restrict__ C1, TC* __restrict__ C2)
{
    __shared__ short As[128 * 32];
    __shared__ short Bs[128 * 32];

    const int t    = threadIdx.x;
    const int lane = t & 63;
    const int w    = t >> 6;
    const int wm   = (w >> 1) * 64;
    const int wn   = (w & 1) * 64;
    const int quad = lane >> 4;
    const int l16  = lane & 15;

    const int g = blockIdx.x >> 3;
    const __hip_bfloat16* A = (g == 0) ? A0 : (g == 1 ? A1 : A2);
    const float* bias       = (g == 0) ? b0 : (g == 1 ? b1 : b2);
    TC* C                   = (g == 0) ? C0 : (g == 1 ? C1 : C2);
    const int    bm  = blockIdx.y * 128;
    const int    bnl = (blockIdx.x & 7) * 128;
    const size_t bng = (size_t)blockIdx.x * 128;

    f32x4 acc[4][4];
#pragma unroll
    for (int i = 0; i < 4; i++)
#pragma unroll
        for (int j = 0; j < 4; j++)
            acc[i][j] = (f32x4){0.f, 0.f, 0.f, 0.f};

    for (int kt = 0; kt < DMODEL; kt += 32) {
        __syncthreads();
#pragma unroll
        for (int i = 0; i < 2; i++) {
            const int s  = i * 256 + t;
            const int br = s >> 2;
            const int c  = ((s & 3) - (br >> 1)) & 3;
            async16(B + (bng + br) * DMODEL + kt + c * 8,
                    &Bs[(i * 256 + (w << 6)) * 8]);
            async16(A + (size_t)(bm + br) * DMODEL + kt + c * 8,
                    &As[(i * 256 + (w << 6)) * 8]);
        }
        __syncthreads();

        bf16x8 af[4], bf[4];
#pragma unroll
        for (int mi = 0; mi < 4; mi++) {
            const int row = wm + mi * 16 + l16;
            const int pc  = (quad + (row >> 1)) & 3;
            af[mi] = *(const bf16x8*)&As[row * 32 + pc * 8];
        }
#pragma unroll
        for (int ni = 0; ni < 4; ni++) {
            const int row = wn + ni * 16 + l16;
            const int pc  = (quad + (row >> 1)) & 3;
            bf[ni] = *(const bf16x8*)&Bs[row * 32 + pc * 8];
        }
#pragma unroll
        for (int mi = 0; mi < 4; mi++)
#pragma unroll
            for (int ni = 0; ni < 4; ni++)
                acc[mi][ni] = __builtin_amdgcn_mfma_f32_16x16x32_bf16(
                    af[mi], bf[ni], acc[mi][ni], 0, 0, 0);
    }

#pragma unroll
    for (int mi = 0; mi < 4; mi++) {
#pragma unroll
        for (int ni = 0; ni < 4; ni++) {
            const int row0 = bm + wm + mi * 16 + quad * 4;
            const int coll = bnl + wn + ni * 16 + l16;
            const float bb = bias[coll];
#pragma unroll
            for (int r = 0; r < 4; r++) {
                const float val = acc[mi][ni][r] + bb;
                if constexpr (std::is_same<TC, float>::value)
                    C[(size_t)(row0 + r) * DMODEL + coll] = val;
                else
                    C[(size_t)(row0 + r) * DMODEL + coll] = __float2bfloat16(val);
            }
        }
    }
}

// ---------------- Workgroup split-K flash attention, 128-key stages ----------------
// block = 4 waves, 64 q-rows (slab st) x one 512-key chunk -> <=4 stages of 128 keys.
// Per stage/wave: 16 QK-MFMA + ONE exp2-softmax + P-roundtrip + 16 PV-MFMA, 2 barriers.
// Softmax runs in exp2 domain: scores pre-scaled by (1/32)*log2(e).
#define SCL2 0.04508422f   // 0.03125 * log2(e)
#define LPS  140           // P stride (shorts): 4-row stride = 24 mod 32 dwords -> cf writes

__global__ __launch_bounds__(256, 3)
void attn_flash_wg(const __hip_bfloat16* __restrict__ qp,
                   const __hip_bfloat16* __restrict__ kp,
                   const __hip_bfloat16* __restrict__ vt,
                   __hip_bfloat16* __restrict__ po0,
                   __hip_bfloat16* __restrict__ po1,
                   float* __restrict__ ml)
{
    __shared__ short Ks[128 * 64];   // [key][dh], 8-chunk xor swizzle per row
    __shared__ short Vs[64 * 128];   // [dh][key], 16-chunk xor swizzle per row
    __shared__ short Ps[64 * LPS];

    const int t    = threadIdx.x;
    const int lane = t & 63;
    const int w    = t >> 6;
    const int l16  = lane & 15;
    const int quad = lane >> 4;

    // XCD swizzle (bh fixed per XCD slot) + heavy chunks first
    const int bh   = blockIdx.x & 31;
    const int cidx = 79 - ((int)blockIdx.x >> 5);
    int st, c;
    if (cidx < 8)       { st = cidx; c = 0; }
    else if (cidx < 24) { const int u = cidx - 8;  st = 8 + (u >> 1); c = u & 1; }
    else if (cidx < 48) { const int u = cidx - 24; const int q3 = u / 3; st = 16 + q3; c = u - 3 * q3; }
    else                { const int u = cidx - 48; st = 24 + (u >> 2); c = u & 3; }
    const int bid = bh * 80 +
        ((st < 8) ? st : (st < 16) ? 8 + 2 * (st - 8) : (st < 24) ? 24 + 3 * (st - 16)
                                                      : 48 + 4 * (st - 24)) + c;
    const int b = bh >> 4;
    const int h = bh & 15;

    // Q fragments (A-layout): rows 64st+16w+l16, k = quad*8 (+32)
    const __hip_bfloat16* qptr =
        qp + (size_t)(b * SEQ + 64 * st + 16 * w + l16) * DMODEL + h * DH + quad * 8;
    bf16x8 aq0 = *(const bf16x8*)qptr;
    bf16x8 aq1 = *(const bf16x8*)(qptr + 32);

    float m[4], l[4];
    f32x4 oc[4];
#pragma unroll
    for (int r = 0; r < 4; r++) { m[r] = -__builtin_inff(); l[r] = 0.f; }
#pragma unroll
    for (int dt = 0; dt < 4; dt++) oc[dt] = (f32x4){0.f, 0.f, 0.f, 0.f};

    const __hip_bfloat16* kbase = kp + (size_t)(b * SEQ) * DMODEL + h * DH;
    const __hip_bfloat16* vbase = vt + (size_t)(bh * DH) * SEQ;

    const int kmax   = 64 * st + 64;
    const int key_lo = 512 * c;
    const int krem   = kmax - key_lo;                 // 64..512
    const int nst    = (krem + 127) >> 7;             // 1..4 stages of 128 keys
    const int rowb   = 64 * st + 16 * w + quad * 4;   // +r = lane's q-rows

    for (int js = 0; js < nst; ++js) {
        const int key0 = key_lo + (js << 7);
        __syncthreads();   // prev stage's Ks/Vs reads complete
        // ---- stage K [128 keys][64 dh] and V^T [64 dh][128 keys] ----
#pragma unroll
        for (int i = 0; i < 4; i++) {
            const int p  = i * 256 + t;               // physical 16B segment (0..1023)
            const int kr = p >> 3;                    // K row (key)
            const int kc = ((p & 7) - kr) & 7;        // logical K chunk
            async16(kbase + (size_t)(key0 + kr) * DMODEL + kc * 8,
                    &Ks[(i * 256 + (w << 6)) * 8]);
            const int vr = p >> 4;                    // V row (dh)
            const int vc = ((p & 15) - vr) & 15;      // logical V chunk
            async16(vbase + (size_t)vr * SEQ + key0 + vc * 8,
                    &Vs[(i * 256 + (w << 6)) * 8]);
        }
        __syncthreads();   // drains async queue

        // ---- S = Q K^T over 128 keys (8 col-tiles) ----
        f32x4 sc[8];
#pragma unroll
        for (int ct = 0; ct < 8; ct++) {
            const int row = 16 * ct + l16;
            bf16x8 bk0 = *(const bf16x8*)&Ks[row * 64 + ((quad + row) & 7) * 8];
            bf16x8 bk1 = *(const bf16x8*)&Ks[row * 64 + ((quad + 4 + row) & 7) * 8];
            sc[ct] = __builtin_amdgcn_mfma_f32_16x16x32_bf16(
                aq0, bk0, (f32x4){0.f, 0.f, 0.f, 0.f}, 0, 0, 0);
            sc[ct] = __builtin_amdgcn_mfma_f32_16x16x32_bf16(aq1, bk1, sc[ct], 0, 0, 0);
        }

        // ---- scale (exp2 domain) + causal mask (only diagonal-crossing stage) ----
        if (key0 + 128 > 64 * st) {
#pragma unroll
            for (int ct = 0; ct < 8; ct++)
#pragma unroll
                for (int r = 0; r < 4; r++) {
                    float v = sc[ct][r] * SCL2;
                    if (key0 + 16 * ct + l16 > rowb + r) v = -__builtin_inff();
                    sc[ct][r] = v;
                }
        } else {
#pragma unroll
            for (int ct = 0; ct < 8; ct++)
#pragma unroll
                for (int r = 0; r < 4; r++) sc[ct][r] *= SCL2;
        }

        // ---- ONE online softmax over 128 cols (exp2 domain) ----
        float alpha[4];
#pragma unroll
        for (int r = 0; r < 4; r++) {
            float mx = sc[0][r];
#pragma unroll
            for (int ct = 1; ct < 8; ct++) mx = fmaxf(mx, sc[ct][r]);
#pragma unroll
            for (int d = 1; d < 16; d <<= 1) mx = fmaxf(mx, __shfl_xor(mx, d));
            const float mn = fmaxf(m[r], mx);
            alpha[r] = exp2f(m[r] - mn);
            float sum = 0.f;
#pragma unroll
            for (int ct = 0; ct < 8; ct++) {
                const float e = exp2f(sc[ct][r] - mn);
                sc[ct][r] = e;
                sum += e;
            }
#pragma unroll
            for (int d = 1; d < 16; d <<= 1) sum += __shfl_xor(sum, d);
            l[r] = alpha[r] * l[r] + sum;
            m[r] = mn;
        }

        // ---- P: C-layout -> A-layout via wave-local LDS roundtrip ----
#pragma unroll
        for (int ct = 0; ct < 8; ct++)
#pragma unroll
            for (int r = 0; r < 4; r++)
                Ps[(16 * w + quad * 4 + r) * LPS + 16 * ct + l16] = f2bs(sc[ct][r]);
        bf16x8 ap[4];
#pragma unroll
        for (int kk = 0; kk < 4; kk++)
            ap[kk] = *(const bf16x8*)&Ps[(16 * w + l16) * LPS + kk * 32 + quad * 8];

        // ---- O = alpha*O + P V (K=128 -> 4 mfma per dh-tile) ----
#pragma unroll
        for (int dt = 0; dt < 4; dt++)
#pragma unroll
            for (int r = 0; r < 4; r++) oc[dt][r] *= alpha[r];
#pragma unroll
        for (int dt = 0; dt < 4; dt++) {
            const int row = 16 * dt + l16;   // dh row in Vs
#pragma unroll
            for (int kk = 0; kk < 4; kk++) {
                const int pc = ((kk * 4 + quad) + row) & 15;
                bf16x8 bv = *(const bf16x8*)&Vs[row * 128 + pc * 8];
                oc[dt] = __builtin_amdgcn_mfma_f32_16x16x32_bf16(ap[kk], bv, oc[dt], 0, 0, 0);
            }
        }
    }

    // ---- write unnormalized partial [64][64] bf16 + m,l fp32 (exp2 domain) ----
    __hip_bfloat16* pp = (bid < 2048) ? po0 + (size_t)bid * 4096
                                      : po1 + (size_t)(bid - 2048) * 4096;
#pragma unroll
    for (int r = 0; r < 4; r++) {
        const int row = 16 * w + quad * 4 + r;
#pragma unroll
        for (int dt = 0; dt < 4; dt++)
            pp[row * 64 + 16 * dt + l16] = __float2bfloat16(oc[dt][r]);
        if (l16 == 0) {
            ml[(size_t)bid * 128 + row]      = m[r];
            ml[(size_t)bid * 128 + 64 + row] = l[r];
        }
    }
}

// ---------------- merge <=4 chunk-partials per (bh, slab); exp2 domain ----------------
__global__ __launch_bounds__(256)
void attn_reduce(const __hip_bfloat16* __restrict__ po0, const __hip_bfloat16* __restrict__ po1,
                 const float* __restrict__ ml, __hip_bfloat16* __restrict__ ao)
{
    const int col = threadIdx.x & 63;
    const int r0  = threadIdx.x >> 6;          // 0..3
    const int bh  = blockIdx.x >> 5;
    const int st  = blockIdx.x & 31;
    const int nch = (st >> 3) + 1;
    const int pre = (st < 8) ? st : (st < 16) ? 8 + 2 * (st - 8)
                  : (st < 24) ? 24 + 3 * (st - 16) : 48 + 4 * (st - 24);
    const int bid0 = bh * 80 + pre;
    const int b = bh >> 4;
    const int h = bh & 15;

    for (int i = 0; i < 16; i++) {
        const int row = r0 + 4 * i;
        float M = -__builtin_inff();
        for (int cc = 0; cc < nch; cc++)
            M = fmaxf(M, ml[(size_t)(bid0 + cc) * 128 + row]);
        float L = 0.f, O = 0.f;
        for (int cc = 0; cc < nch; cc++) {
            const int bidc = bid0 + cc;
            const float wgt = exp2f(ml[(size_t)bidc * 128 + row] - M);
            L += ml[(size_t)bidc * 128 + 64 + row] * wgt;
            const __hip_bfloat16* pp = (bidc < 2048) ? po0 + (size_t)bidc * 4096
                                                     : po1 + (size_t)(bidc - 2048) * 4096;
            O += wgt * __bfloat162float(pp[row * 64 + col]);
        }
        ao[(size_t)(b * SEQ + 64 * st + row) * DMODEL + h * DH + col] =
            __float2bfloat16(O / L);
    }
}

// ---------------- launch ----------------
extern "C" void kernel_launch(void* const* d_in, const int* in_sizes, int n_in,
                              void* d_out, int out_size, void* d_ws, size_t ws_size,
                              hipStream_t stream) {
    const float* q  = (const float*)d_in[0];
    const float* k  = (const float*)d_in[1];
    const float* v  = (const float*)d_in[2];
    const float* Wq = (const float*)d_in[3];
    const float* bq = (const float*)d_in[4];
    const float* Wk = (const float*)d_in[5];
    const float* bk = (const float*)d_in[6];
    const float* Wv = (const float*)d_in[7];
    const float* bv = (const float*)d_in[8];
    const float* Wo = (const float*)d_in[9];
    const float* bo = (const float*)d_in[10];
    float* out = (float*)d_out;

    __hip_bfloat16* Wqkv = (__hip_bfloat16*)d_ws;
    __hip_bfloat16* Wob  = Wqkv + (size_t)3072 * 1024;
    __hip_bfloat16* qp   = Wob  + (size_t)1024 * 1024;
    __hip_bfloat16* kp   = qp   + (size_t)MROWS * DMODEL;
    __hip_bfloat16* vp   = kp   + (size_t)MROWS * DMODEL;
    __hip_bfloat16* vb   = vp   + (size_t)MROWS * DMODEL;
    float*          mlb  = (float*)(vb + (size_t)MROWS * DMODEL);   // 2560*128 floats
    __hip_bfloat16* qb   = (__hip_bfloat16*)d_out;
    __hip_bfloat16* kb   = qb + (size_t)MROWS * DMODEL;
    __hip_bfloat16* vtg  = vb;                       // vb dead after QKV gemm
    __hip_bfloat16* ao   = vp;                       // vp dead after transpose_v
    __hip_bfloat16* po0  = (__hip_bfloat16*)d_out;   // qb/kb dead after QKV gemm
    __hip_bfloat16* po1  = Wqkv;                     // Wqkv dead after QKV gemm

    hipLaunchKernelGGL(convert_all, dim3(8192), dim3(256), 0, stream,
                       Wq, Wk, Wv, Wo, q, k, v, Wqkv, Wob, qb, kb, vb);

    hipLaunchKernelGGL((gemm_bt<__hip_bfloat16>), dim3(24, 32), dim3(256), 0, stream,
                       qb, kb, vb, Wqkv, bq, bk, bv, qp, kp, vp);

    hipLaunchKernelGGL(transpose_v, dim3(1024), dim3(256), 0, stream, vp, vtg);

    hipLaunchKernelGGL(attn_flash_wg, dim3(2560), dim3(256), 0, stream,
                       qp, kp, vtg, po0, po1, mlb);

    hipLaunchKernelGGL(attn_reduce, dim3(1024), dim3(256), 0, stream,
                       po0, po1, mlb, ao);

    hipLaunchKernelGGL((gemm_bt<float>), dim3(8, 32), dim3(256), 0, stream,
                       ao, ao, ao, Wob, bo, bo, bo, out, out, out);
}

// Round 10
// 287.687 us; speedup vs baseline: 1.1252x; 1.1252x over previous
//
#include <hip/hip_runtime.h>
#include <hip/hip_bf16.h>
#include <stdint.h>
#include <type_traits>

#define NHEAD  16
#define DMODEL 1024
#define BATCH  2
#define SEQ    2048
#define DH     64
#define MROWS  (BATCH*SEQ)   // 4096

typedef __attribute__((ext_vector_type(8))) short bf16x8;
typedef __attribute__((ext_vector_type(4))) float f32x4;

__device__ inline short f2bs(float f) {
    __hip_bfloat16 h = __float2bfloat16(f);
    return *reinterpret_cast<short*>(&h);
}

// async global -> LDS, 16B per lane. LDS dest = wave-uniform base + lane*16.
__device__ inline void async16(const void* g, void* l) {
    __builtin_amdgcn_global_load_lds(
        (__attribute__((address_space(1))) void*)g,
        (__attribute__((address_space(3))) void*)l, 16, 0, 0);
}

// ------------- fp32 -> bf16 pre-convert: weights (4M) + q,k,v inputs (12M) -------------
__global__ __launch_bounds__(256)
void convert_all(const float* __restrict__ Wq, const float* __restrict__ Wk,
                 const float* __restrict__ Wv, const float* __restrict__ Wo,
                 const float* __restrict__ q, const float* __restrict__ k,
                 const float* __restrict__ v,
                 __hip_bfloat16* __restrict__ Wqkv, __hip_bfloat16* __restrict__ Wob,
                 __hip_bfloat16* __restrict__ qb, __hip_bfloat16* __restrict__ kb,
                 __hip_bfloat16* __restrict__ vb)
{
    const int idx = (blockIdx.x * 256 + threadIdx.x) * 8;
    const float* src;
    __hip_bfloat16* dst;
    if (idx < 3 * 1048576) {
        const int g = idx >> 20;
        src = (g == 0 ? Wq : (g == 1 ? Wk : Wv)) + (idx & 1048575);
        dst = Wqkv + idx;
    } else if (idx < 4 * 1048576) {
        src = Wo + (idx - 3 * 1048576);
        dst = Wob + (idx - 3 * 1048576);
    } else if (idx < 8 * 1048576) {
        src = q + (idx - 4 * 1048576);
        dst = qb + (idx - 4 * 1048576);
    } else if (idx < 12 * 1048576) {
        src = k + (idx - 8 * 1048576);
        dst = kb + (idx - 8 * 1048576);
    } else {
        src = v + (idx - 12 * 1048576);
        dst = vb + (idx - 12 * 1048576);
    }
    float4 f0 = *(const float4*)src;
    float4 f1 = *(const float4*)(src + 4);
    short o[8];
    o[0] = f2bs(f0.x); o[1] = f2bs(f0.y); o[2] = f2bs(f0.z); o[3] = f2bs(f0.w);
    o[4] = f2bs(f1.x); o[5] = f2bs(f1.y); o[6] = f2bs(f1.z); o[7] = f2bs(f1.w);
    *(uint4*)dst = *(uint4*)o;
}

// ---------------- V-projection transpose: vp[4096][1024] -> vt[b][h][64][2048] ----------------
__global__ __launch_bounds__(256)
void transpose_v(const __hip_bfloat16* __restrict__ vp, __hip_bfloat16* __restrict__ vt)
{
    __shared__ short L[64 * 72];
    const int t  = threadIdx.x;
    const int st = blockIdx.x & 63;
    const int ht = blockIdx.x >> 6;
    {
        const int r = t >> 2, cs = (t & 3) * 16;
        const __hip_bfloat16* src = vp + (size_t)(st * 64 + r) * DMODEL + ht * 64 + cs;
        *(uint4*)&L[r * 72 + cs]     = *(const uint4*)src;
        *(uint4*)&L[r * 72 + cs + 8] = *(const uint4*)(src + 8);
    }
    __syncthreads();
    const int d  = t >> 2;
    const int ss = (t & 3) * 16;
    const int m0 = st * 64;
    const int b  = m0 >> 11;
    const int s0 = (m0 & 2047) + ss;
    short o[16];
#pragma unroll
    for (int i = 0; i < 16; i++) o[i] = L[(ss + i) * 72 + d];
    __hip_bfloat16* dst = vt + ((size_t)((b * NHEAD + ht) * DH + d)) * SEQ + s0;
    *(uint4*)dst       = *(uint4*)&o[0];
    *(uint4*)(dst + 8) = *(uint4*)&o[8];
}

// ---------------- GEMM: C[:,grp] = A_grp[M,K] @ B[N,K]^T + bias (all-bf16 inputs) ----------------
// BK=64: 32 MFMA per barrier-pair (was 16). XOR row-swizzle (8 chunks/row) -> 2-way reads.
template <typename TC>
__global__ __launch_bounds__(256, 3)
void gemm_bt(const __hip_bfloat16* __restrict__ A0, const __hip_bfloat16* __restrict__ A1,
             const __hip_bfloat16* __restrict__ A2,
             const __hip_bfloat16* __restrict__ B,
             const float* __restrict__ b0, const float* __restrict__ b1, const float* __restrict__ b2,
             TC* __restrict__ C0, TC* __restrict__ C1, TC* __restrict__ C2)
{
    __shared__ short As[128 * 64];
    __shared__ short Bs[128 * 64];

    const int t    = threadIdx.x;
    const int lane = t & 63;
    const int w    = t >> 6;
    const int wm   = (w >> 1) * 64;
    const int wn   = (w & 1) * 64;
    const int quad = lane >> 4;
    const int l16  = lane & 15;

    const int g = blockIdx.x >> 3;
    const __hip_bfloat16* A = (g == 0) ? A0 : (g == 1 ? A1 : A2);
    const float* bias       = (g == 0) ? b0 : (g == 1 ? b1 : b2);
    TC* C                   = (g == 0) ? C0 : (g == 1 ? C1 : C2);
    const int    bm  = blockIdx.y * 128;
    const int    bnl = (blockIdx.x & 7) * 128;
    const size_t bng = (size_t)blockIdx.x * 128;

    f32x4 acc[4][4];
#pragma unroll
    for (int i = 0; i < 4; i++)
#pragma unroll
        for (int j = 0; j < 4; j++)
            acc[i][j] = (f32x4){0.f, 0.f, 0.f, 0.f};

    for (int kt = 0; kt < DMODEL; kt += 64) {
        __syncthreads();   // prev iteration's fragment reads done
        // stage 128x64 tiles: physical 16B segment p -> row p>>3, logical chunk ((p&7)-row)&7
#pragma unroll
        for (int i = 0; i < 4; i++) {
            const int p  = i * 256 + t;          // 0..1023
            const int br = p >> 3;
            const int c8 = ((p & 7) - br) & 7;
            async16(B + (bng + br) * DMODEL + kt + c8 * 8,
                    &Bs[(i * 256 + (w << 6)) * 8]);
            async16(A + (size_t)(bm + br) * DMODEL + kt + c8 * 8,
                    &As[(i * 256 + (w << 6)) * 8]);
        }
        __syncthreads();   // drains async queue

#pragma unroll
        for (int kk = 0; kk < 2; kk++) {
            bf16x8 af[4], bf[4];
#pragma unroll
            for (int mi = 0; mi < 4; mi++) {
                const int row = wm + mi * 16 + l16;
                const int pc  = ((quad + 4 * kk) + row) & 7;
                af[mi] = *(const bf16x8*)&As[row * 64 + pc * 8];
            }
#pragma unroll
            for (int ni = 0; ni < 4; ni++) {
                const int row = wn + ni * 16 + l16;
                const int pc  = ((quad + 4 * kk) + row) & 7;
                bf[ni] = *(const bf16x8*)&Bs[row * 64 + pc * 8];
            }
#pragma unroll
            for (int mi = 0; mi < 4; mi++)
#pragma unroll
                for (int ni = 0; ni < 4; ni++)
                    acc[mi][ni] = __builtin_amdgcn_mfma_f32_16x16x32_bf16(
                        af[mi], bf[ni], acc[mi][ni], 0, 0, 0);
        }
    }

#pragma unroll
    for (int mi = 0; mi < 4; mi++) {
#pragma unroll
        for (int ni = 0; ni < 4; ni++) {
            const int row0 = bm + wm + mi * 16 + quad * 4;
            const int coll = bnl + wn + ni * 16 + l16;
            const float bb = bias[coll];
#pragma unroll
            for (int r = 0; r < 4; r++) {
                const float val = acc[mi][ni][r] + bb;
                if constexpr (std::is_same<TC, float>::value)
                    C[(size_t)(row0 + r) * DMODEL + coll] = val;
                else
                    C[(size_t)(row0 + r) * DMODEL + coll] = __float2bfloat16(val);
            }
        }
    }
}

// ---------------- Workgroup split-K flash attention (R8 config — proven 81 us) ----------------
// block = 4 waves, 64 q-rows (slab st) x one 512-key chunk. Per 64-key stage:
// async16-staged K + V^T tiles (8-chunk XOR swizzle), 8 QK-MFMA + softmax +
// P-roundtrip + 8 PV-MFMA per wave, 2 barriers. 26 KB LDS -> 6 blocks/CU.
#define LPS 76

__global__ __launch_bounds__(256, 6)
void attn_flash_wg(const __hip_bfloat16* __restrict__ qp,
                   const __hip_bfloat16* __restrict__ kp,
                   const __hip_bfloat16* __restrict__ vt,
                   __hip_bfloat16* __restrict__ po0,
                   __hip_bfloat16* __restrict__ po1,
                   float* __restrict__ ml)
{
    __shared__ short Ks[64 * 64];
    __shared__ short Vs[64 * 64];
    __shared__ short Ps[64 * LPS];

    const int t    = threadIdx.x;
    const int lane = t & 63;
    const int w    = t >> 6;
    const int l16  = lane & 15;
    const int quad = lane >> 4;

    const int bh   = blockIdx.x & 31;
    const int cidx = 79 - ((int)blockIdx.x >> 5);
    int st, c;
    if (cidx < 8)       { st = cidx; c = 0; }
    else if (cidx < 24) { const int u = cidx - 8;  st = 8 + (u >> 1); c = u & 1; }
    else if (cidx < 48) { const int u = cidx - 24; const int q3 = u / 3; st = 16 + q3; c = u - 3 * q3; }
    else                { const int u = cidx - 48; st = 24 + (u >> 2); c = u & 3; }
    const int bid = bh * 80 +
        ((st < 8) ? st : (st < 16) ? 8 + 2 * (st - 8) : (st < 24) ? 24 + 3 * (st - 16)
                                                      : 48 + 4 * (st - 24)) + c;
    const int b = bh >> 4;
    const int h = bh & 15;

    const __hip_bfloat16* qptr =
        qp + (size_t)(b * SEQ + 64 * st + 16 * w + l16) * DMODEL + h * DH + quad * 8;
    bf16x8 aq0 = *(const bf16x8*)qptr;
    bf16x8 aq1 = *(const bf16x8*)(qptr + 32);

    float m[4], l[4];
    f32x4 oc[4];
#pragma unroll
    for (int r = 0; r < 4; r++) { m[r] = -__builtin_inff(); l[r] = 0.f; }
#pragma unroll
    for (int dt = 0; dt < 4; dt++) oc[dt] = (f32x4){0.f, 0.f, 0.f, 0.f};

    const __hip_bfloat16* kbase = kp + (size_t)(b * SEQ) * DMODEL + h * DH;
    const __hip_bfloat16* vbase = vt + (size_t)(bh * DH) * SEQ;

    const int kmax   = 64 * st + 64;
    const int key_lo = 512 * c;
    const int nst    = (min(key_lo + 512, kmax) - key_lo) >> 6;
    const int rowb   = 64 * st + 16 * w + quad * 4;

    for (int js = 0; js < nst; ++js) {
        const int key0 = key_lo + (js << 6);
        __syncthreads();
#pragma unroll
        for (int i = 0; i < 2; i++) {
            const int p   = i * 256 + t;
            const int row = p >> 3;
            const int c8  = ((p & 7) - row) & 7;
            async16(kbase + (size_t)(key0 + row) * DMODEL + c8 * 8,
                    &Ks[(i * 256 + (w << 6)) * 8]);
            async16(vbase + (size_t)row * SEQ + key0 + c8 * 8,
                    &Vs[(i * 256 + (w << 6)) * 8]);
        }
        __syncthreads();

        f32x4 sc[4];
#pragma unroll
        for (int ct = 0; ct < 4; ct++) {
            const int row = 16 * ct + l16;
            bf16x8 bk0 = *(const bf16x8*)&Ks[row * 64 + ((quad + row) & 7) * 8];
            bf16x8 bk1 = *(const bf16x8*)&Ks[row * 64 + ((quad + 4 + row) & 7) * 8];
            sc[ct] = __builtin_amdgcn_mfma_f32_16x16x32_bf16(
                aq0, bk0, (f32x4){0.f, 0.f, 0.f, 0.f}, 0, 0, 0);
            sc[ct] = __builtin_amdgcn_mfma_f32_16x16x32_bf16(aq1, bk1, sc[ct], 0, 0, 0);
        }

        if (key0 == 64 * st) {
#pragma unroll
            for (int ct = 0; ct < 4; ct++)
#pragma unroll
                for (int r = 0; r < 4; r++) {
                    float v = sc[ct][r] * 0.03125f;
                    if (key0 + 16 * ct + l16 > rowb + r) v = -__builtin_inff();
                    sc[ct][r] = v;
                }
        } else {
#pragma unroll
            for (int ct = 0; ct < 4; ct++)
#pragma unroll
                for (int r = 0; r < 4; r++) sc[ct][r] *= 0.03125f;
        }

        float alpha[4];
#pragma unroll
        for (int r = 0; r < 4; r++) {
            float mx = fmaxf(fmaxf(sc[0][r], sc[1][r]), fmaxf(sc[2][r], sc[3][r]));
#pragma unroll
            for (int d = 1; d < 16; d <<= 1) mx = fmaxf(mx, __shfl_xor(mx, d));
            const float mn = fmaxf(m[r], mx);
            alpha[r] = __expf(m[r] - mn);
            float sum = 0.f;
#pragma unroll
            for (int ct = 0; ct < 4; ct++) {
                const float e = __expf(sc[ct][r] - mn);
                sc[ct][r] = e;
                sum += e;
            }
#pragma unroll
            for (int d = 1; d < 16; d <<= 1) sum += __shfl_xor(sum, d);
            l[r] = alpha[r] * l[r] + sum;
            m[r] = mn;
        }

#pragma unroll
        for (int ct = 0; ct < 4; ct++)
#pragma unroll
            for (int r = 0; r < 4; r++)
                Ps[(16 * w + quad * 4 + r) * LPS + 16 * ct + l16] = f2bs(sc[ct][r]);
        bf16x8 ap0 = *(const bf16x8*)&Ps[(16 * w + l16) * LPS + quad * 8];
        bf16x8 ap1 = *(const bf16x8*)&Ps[(16 * w + l16) * LPS + 32 + quad * 8];

#pragma unroll
        for (int dt = 0; dt < 4; dt++)
#pragma unroll
            for (int r = 0; r < 4; r++) oc[dt][r] *= alpha[r];
#pragma unroll
        for (int dt = 0; dt < 4; dt++) {
            const int row = 16 * dt + l16;
            bf16x8 bv0 = *(const bf16x8*)&Vs[row * 64 + ((quad + row) & 7) * 8];
            bf16x8 bv1 = *(const bf16x8*)&Vs[row * 64 + ((quad + 4 + row) & 7) * 8];
            oc[dt] = __builtin_amdgcn_mfma_f32_16x16x32_bf16(ap0, bv0, oc[dt], 0, 0, 0);
            oc[dt] = __builtin_amdgcn_mfma_f32_16x16x32_bf16(ap1, bv1, oc[dt], 0, 0, 0);
        }
    }

    __hip_bfloat16* pp = (bid < 2048) ? po0 + (size_t)bid * 4096
                                      : po1 + (size_t)(bid - 2048) * 4096;
#pragma unroll
    for (int r = 0; r < 4; r++) {
        const int row = 16 * w + quad * 4 + r;
#pragma unroll
        for (int dt = 0; dt < 4; dt++)
            pp[row * 64 + 16 * dt + l16] = __float2bfloat16(oc[dt][r]);
        if (l16 == 0) {
            ml[(size_t)bid * 128 + row]      = m[r];
            ml[(size_t)bid * 128 + 64 + row] = l[r];
        }
    }
}

// ---------------- merge <=4 chunk-partials per (bh, slab) ----------------
__global__ __launch_bounds__(256)
void attn_reduce(const __hip_bfloat16* __restrict__ po0, const __hip_bfloat16* __restrict__ po1,
                 const float* __restrict__ ml, __hip_bfloat16* __restrict__ ao)
{
    const int col = threadIdx.x & 63;
    const int r0  = threadIdx.x >> 6;
    const int bh  = blockIdx.x >> 5;
    const int st  = blockIdx.x & 31;
    const int nch = (st >> 3) + 1;
    const int pre = (st < 8) ? st : (st < 16) ? 8 + 2 * (st - 8)
                  : (st < 24) ? 24 + 3 * (st - 16) : 48 + 4 * (st - 24);
    const int bid0 = bh * 80 + pre;
    const int b = bh >> 4;
    const int h = bh & 15;

    for (int i = 0; i < 16; i++) {
        const int row = r0 + 4 * i;
        float M = -__builtin_inff();
        for (int cc = 0; cc < nch; cc++)
            M = fmaxf(M, ml[(size_t)(bid0 + cc) * 128 + row]);
        float L = 0.f, O = 0.f;
        for (int cc = 0; cc < nch; cc++) {
            const int bidc = bid0 + cc;
            const float wgt = __expf(ml[(size_t)bidc * 128 + row] - M);
            L += ml[(size_t)bidc * 128 + 64 + row] * wgt;
            const __hip_bfloat16* pp = (bidc < 2048) ? po0 + (size_t)bidc * 4096
                                                     : po1 + (size_t)(bidc - 2048) * 4096;
            O += wgt * __bfloat162float(pp[row * 64 + col]);
        }
        ao[(size_t)(b * SEQ + 64 * st + row) * DMODEL + h * DH + col] =
            __float2bfloat16(O / L);
    }
}

// ---------------- launch ----------------
extern "C" void kernel_launch(void* const* d_in, const int* in_sizes, int n_in,
                              void* d_out, int out_size, void* d_ws, size_t ws_size,
                              hipStream_t stream) {
    const float* q  = (const float*)d_in[0];
    const float* k  = (const float*)d_in[1];
    const float* v  = (const float*)d_in[2];
    const float* Wq = (const float*)d_in[3];
    const float* bq = (const float*)d_in[4];
    const float* Wk = (const float*)d_in[5];
    const float* bk = (const float*)d_in[6];
    const float* Wv = (const float*)d_in[7];
    const float* bv = (const float*)d_in[8];
    const float* Wo = (const float*)d_in[9];
    const float* bo = (const float*)d_in[10];
    float* out = (float*)d_out;

    __hip_bfloat16* Wqkv = (__hip_bfloat16*)d_ws;
    __hip_bfloat16* Wob  = Wqkv + (size_t)3072 * 1024;
    __hip_bfloat16* qp   = Wob  + (size_t)1024 * 1024;
    __hip_bfloat16* kp   = qp   + (size_t)MROWS * DMODEL;
    __hip_bfloat16* vp   = kp   + (size_t)MROWS * DMODEL;
    __hip_bfloat16* vb   = vp   + (size_t)MROWS * DMODEL;
    float*          mlb  = (float*)(vb + (size_t)MROWS * DMODEL);   // 2560*128 floats
    __hip_bfloat16* qb   = (__hip_bfloat16*)d_out;
    __hip_bfloat16* kb   = qb + (size_t)MROWS * DMODEL;
    __hip_bfloat16* vtg  = vb;                       // vb dead after QKV gemm
    __hip_bfloat16* ao   = vp;                       // vp dead after transpose_v
    __hip_bfloat16* po0  = (__hip_bfloat16*)d_out;   // qb/kb dead after QKV gemm
    __hip_bfloat16* po1  = Wqkv;                     // Wqkv dead after QKV gemm

    hipLaunchKernelGGL(convert_all, dim3(8192), dim3(256), 0, stream,
                       Wq, Wk, Wv, Wo, q, k, v, Wqkv, Wob, qb, kb, vb);

    hipLaunchKernelGGL((gemm_bt<__hip_bfloat16>), dim3(24, 32), dim3(256), 0, stream,
                       qb, kb, vb, Wqkv, bq, bk, bv, qp, kp, vp);

    hipLaunchKernelGGL(transpose_v, dim3(1024), dim3(256), 0, stream, vp, vtg);

    hipLaunchKernelGGL(attn_flash_wg, dim3(2560), dim3(256), 0, stream,
                       qp, kp, vtg, po0, po1, mlb);

    hipLaunchKernelGGL(attn_reduce, dim3(1024), dim3(256), 0, stream,
                       po0, po1, mlb, ao);

    hipLaunchKernelGGL((gemm_bt<float>), dim3(8, 32), dim3(256), 0, stream,
                       ao, ao, ao, Wob, bo, bo, bo, out, out, out);
}